// Round 1
// baseline (8272.477 us; speedup 1.0000x reference)
//
#include <hip/hip_runtime.h>

// ---------------------------------------------------------------------------
// 2-layer LSTM (B=4096, H=512, T=100) + per-step FC(63), fp16 MFMA.
// Grid: 32 teams (128 batch rows each) x 8 blocks (64 hidden units each).
// c-state lives in registers; h exchanged through global fp16 buffers with a
// per-team device-scope barrier once per timestep (parity double-buffered).
// ---------------------------------------------------------------------------

#define HIDN  512
#define SEQL  100
#define BATCH 4096
#define NB    8      // blocks per team
#define BR    128    // batch rows per team

typedef _Float16 f16;
typedef _Float16 half8 __attribute__((ext_vector_type(8)));
typedef float    f32x4 __attribute__((ext_vector_type(4)));
typedef unsigned int u32x4 __attribute__((ext_vector_type(4)));

// ws layout (bytes)
#define OFF_XCAT   0ul                                   // 256*4096*4
#define OFF_X0PT   (OFF_XCAT + 256ul*4096*4)             // 2048*4096*4
#define OFF_WP0    (OFF_X0PT + 2048ul*4096*4)            // 2048*512*2
#define OFF_WP1I   (OFF_WP0  + 2048ul*512*2)
#define OFF_WP1H   (OFF_WP1I + 2048ul*512*2)
#define OFF_FCW    (OFF_WP1H + 2048ul*512*2)             // 64*512*2
#define OFF_B1P    (OFF_FCW  + 64ul*512*2)               // 2048*4
#define OFF_H0     (OFF_B1P  + 2048ul*4)                 // 2*4096*512*2
#define OFF_H1     (OFF_H0   + 2ul*4096*512*2)
#define OFF_FLAGS  (OFF_H1   + 2ul*4096*512*2)           // 32*128*4
#define FLAG_BYTES (32ul*128*4)

// packed row pr = j*256 + g*64 + u  ->  original gate row g*512 + j*64 + u
__device__ __forceinline__ int orow(int pr){
  return (((pr>>6)&3)<<9) | ((pr>>8)<<6) | (pr&63);
}
__device__ __forceinline__ float sigm(float x){ return 1.f/(1.f + __expf(-x)); }
__device__ __forceinline__ float tanhx(float x){ return 1.f - 2.f/(1.f + __expf(2.f*x)); }
__device__ __forceinline__ f32x4 splat4(float v){ f32x4 r; r[0]=v; r[1]=v; r[2]=v; r[3]=v; return r; }

// ---------------- prep 1: xcatT[c][b], c in [0,256) (254 real) ----------------
__global__ __launch_bounds__(256) void k_xcat(
    const int* __restrict__ sl, const int* __restrict__ el,
    const float* __restrict__ sc, const float* __restrict__ ec,
    const float* __restrict__ emb, float* __restrict__ xcatT)
{
  int b = blockIdx.x*256 + threadIdx.x;
  int c = blockIdx.y;
  float v = 0.f;
  if      (c < 64 ) v = emb[sl[b]*64 + c];
  else if (c < 128) v = emb[el[b]*64 + (c-64)];
  else if (c < 191) v = sc[b*63 + (c-128)];
  else if (c < 254) v = ec[b*63 + (c-191)];
  xcatT[c*4096 + b] = v;
}

// ---------------- prep 2: pack recurrent weights to fp16, fc, biases ----------
__global__ __launch_bounds__(256) void k_pack(
    const float* __restrict__ Whh0, const float* __restrict__ Wih1,
    const float* __restrict__ Whh1, const float* __restrict__ fcW,
    const float* __restrict__ bih1, const float* __restrict__ bhh1,
    f16* __restrict__ Wp0, f16* __restrict__ Wp1i, f16* __restrict__ Wp1h,
    f16* __restrict__ fcWp, float* __restrict__ b1p)
{
  int row = blockIdx.x, tid = threadIdx.x;
  if (row < 6144){
    int m  = row >> 11;            // 0:Whh0 1:Wih1 2:Whh1
    int pr = row & 2047;
    const float* src = (m==0) ? Whh0 : (m==1) ? Wih1 : Whh1;
    f16* dst = (m==0) ? Wp0 : (m==1) ? Wp1i : Wp1h;
    int orig = orow(pr);
    dst[pr*512 + tid      ] = (f16)src[orig*512 + tid      ];
    dst[pr*512 + tid + 256] = (f16)src[orig*512 + tid + 256];
  } else if (row < 6208){
    int n = row - 6144;
    float v0 = (n < 63) ? fcW[n*512 + tid      ] : 0.f;
    float v1 = (n < 63) ? fcW[n*512 + tid + 256] : 0.f;
    fcWp[n*512 + tid] = (f16)v0; fcWp[n*512 + tid + 256] = (f16)v1;
  } else {
    int j = row - 6208;
    int orig = (((tid>>6)&3)<<9) | (j<<6) | (tid&63);
    b1p[j*256 + tid] = bih1[orig] + bhh1[orig];
  }
}

// ---------------- prep 3: x0pT[pr][b] = (x @ W_ih0^T + b_ih0 + b_hh0), fp32 ---
__global__ __launch_bounds__(256) void k_x0(
    const float* __restrict__ xcatT, const float* __restrict__ Wih0,
    const float* __restrict__ bih0, const float* __restrict__ bhh0,
    float* __restrict__ x0pT)
{
  int pr0 = blockIdx.x * 16;
  int b   = blockIdx.y * 256 + threadIdx.x;
  float a[16];
#pragma unroll
  for (int i=0;i<16;i++) a[i] = 0.f;
  for (int k=0;k<254;k++){
    float xv = xcatT[k*4096 + b];
#pragma unroll
    for (int i=0;i<16;i++)
      a[i] = fmaf(xv, Wih0[orow(pr0+i)*254 + k], a[i]);   // uniform addr -> s_load
  }
#pragma unroll
  for (int i=0;i<16;i++){
    int orig = orow(pr0+i);
    x0pT[(size_t)(pr0+i)*4096 + b] = a[i] + bih0[orig] + bhh0[orig];
  }
}

// ---------------- main persistent LSTM kernel --------------------------------
__global__ __launch_bounds__(512, 2) void k_lstm(
    const float* __restrict__ x0pT, const f16* __restrict__ Wp0,
    const f16* __restrict__ Wp1i, const f16* __restrict__ Wp1h,
    const f16* __restrict__ fcWp, const float* __restrict__ b1p,
    const float* __restrict__ fcb, f16* __restrict__ h0buf,
    f16* __restrict__ h1buf, unsigned int* __restrict__ flags,
    float* __restrict__ out)
{
  __shared__ f16 Ach[2][128*40];   // 128 rows x (32+8 pad) k, double buffered
  __shared__ f16 Bch[2][256*40];   // 256 gate-rows x (32+8 pad) k

  const int tid  = threadIdx.x;
  const int blk  = blockIdx.x;
  const int j    = blk & 7;        // hidden slice (== XCD with %8 round robin)
  const int team = blk >> 3;       // batch tile
  const int b0   = team * BR;
  const int w = tid >> 6, wr = w >> 2, wc = w & 3;
  const int lane = tid & 63, quad = lane >> 4, lc = lane & 15;
  const int ucol = wc*16 + lc;                 // unit within slice [0,64)
  const bool des = (j == (team & 7));          // designated fc block of team

  const f16* Wb0  = Wp0  + (size_t)(j*256)*512;
  const f16* Wb1i = Wp1i + (size_t)(j*256)*512;
  const f16* Wb1h = Wp1h + (size_t)(j*256)*512;

  float b1v[4];
#pragma unroll
  for (int g=0; g<4; g++) b1v[g] = b1p[j*256 + g*64 + ucol];
  const float fcbv = (ucol < 63) ? fcb[ucol] : 0.f;

  f32x4 c0[4], c1[4];
#pragma unroll
  for (int mt=0; mt<4; mt++){ c0[mt] = splat4(0.f); c1[mt] = splat4(0.f); }

  const int srA = tid >> 2;        // staging row 0..127
  const int ssg = (tid & 3) * 8;   // staging k-offset (elements)
  unsigned int* tflags = flags + team*128;

  auto barrier = [&](int idx){
    __syncthreads();
    if (tid == 0){
      __threadfence();
      __hip_atomic_fetch_add(&tflags[idx], 1u, __ATOMIC_RELAXED, __HIP_MEMORY_SCOPE_AGENT);
      while (__hip_atomic_load(&tflags[idx], __ATOMIC_RELAXED, __HIP_MEMORY_SCOPE_AGENT) < (unsigned)NB)
        __builtin_amdgcn_s_sleep(4);
      __threadfence();
    }
    __syncthreads();
  };

  // pipelined GEMM over nch K-chunks of 32; acc[g][mt] += A*B
  auto GEMM = [&](int nch, auto&& Aat, auto&& Bat, f32x4 (&acc)[4][4],
                  bool dofc, f32x4* fca, int fck0){
    u32x4 ra, rb0, rb1;
    auto ld = [&](int kc){
      const f16* Ap = Aat(kc);
      const f16* Bp = Bat(kc);
      ra  = *(const u32x4*)(Ap + (size_t)srA*HIDN + ssg);
      rb0 = *(const u32x4*)(Bp + (size_t)srA*HIDN + ssg);
      rb1 = *(const u32x4*)(Bp + (size_t)(srA+128)*HIDN + ssg);
    };
    auto st = [&](int kc){
      int bu = kc & 1;
      *(u32x4*)&Ach[bu][srA*40 + ssg]        = ra;
      *(u32x4*)&Bch[bu][srA*40 + ssg]        = rb0;
      *(u32x4*)&Bch[bu][(srA+128)*40 + ssg]  = rb1;
    };
    ld(0); st(0);
    if (nch > 1) ld(1);
    for (int kc=0; kc<nch; kc++){
      __syncthreads();
      if (kc+1 < nch){
        st(kc+1);
        if (kc+2 < nch) ld(kc+2);
      }
      const int bu = kc & 1;
      half8 af[4];
#pragma unroll
      for (int mt=0; mt<4; mt++)
        af[mt] = *(const half8*)&Ach[bu][(wr*64 + mt*16 + lc)*40 + quad*8];
#pragma unroll
      for (int g=0; g<4; g++){
        half8 bf = *(const half8*)&Bch[bu][(g*64 + ucol)*40 + quad*8];
#pragma unroll
        for (int mt=0; mt<4; mt++)
          acc[g][mt] = __builtin_amdgcn_mfma_f32_16x16x32_f16(af[mt], bf, acc[g][mt], 0, 0, 0);
      }
      if (dofc && kc >= fck0){
        half8 fb = *(const half8*)(fcWp + (size_t)ucol*HIDN + (kc-fck0)*32 + quad*8);
#pragma unroll
        for (int mt=0; mt<4; mt++)
          fca[mt] = __builtin_amdgcn_mfma_f32_16x16x32_f16(af[mt], fb, fca[mt], 0, 0, 0);
      }
    }
  };

  for (int t=0; t<SEQL; t++){
    const int p  = t & 1;
    const int pp = (t-1) & 1;
    const f16* h0rd = h0buf + (size_t)pp*BATCH*HIDN + (size_t)b0*HIDN;
    const f16* h1rd = h1buf + (size_t)pp*BATCH*HIDN + (size_t)b0*HIDN;
    f16* h0wr = h0buf + (size_t)p*BATCH*HIDN;
    f16* h1wr = h1buf + (size_t)p*BATCH*HIDN;

    // ----- layer 0: pre0 = x0 + h0(t-1) @ Whh0^T -----
    f32x4 acc[4][4];
#pragma unroll
    for (int g=0; g<4; g++)
#pragma unroll
      for (int mt=0; mt<4; mt++)
        acc[g][mt] = *(const f32x4*)(x0pT + (size_t)(j*256 + g*64 + ucol)*4096
                                     + b0 + wr*64 + mt*16 + quad*4);
    if (t > 0){
      GEMM(16, [&](int kc){ return h0rd + kc*32; },
               [&](int kc){ return Wb0  + kc*32; },
           acc, false, (f32x4*)nullptr, 0);
    }
#pragma unroll
    for (int mt=0; mt<4; mt++){
#pragma unroll
      for (int r=0; r<4; r++){
        float iv = sigm(acc[0][mt][r]);
        float fv = sigm(acc[1][mt][r]);
        float gv = tanhx(acc[2][mt][r]);
        float ov = sigm(acc[3][mt][r]);
        float cn = fv*c0[mt][r] + iv*gv;
        c0[mt][r] = cn;
        float hn = ov * tanhx(cn);
        int row = wr*64 + mt*16 + quad*4 + r;
        h0wr[(size_t)(b0+row)*HIDN + j*64 + ucol] = (f16)hn;
      }
    }
    barrier(t);

    // ----- layer 1: pre1 = b1 + h0(t) @ Wih1^T + h1(t-1) @ Whh1^T  (+ fc y(t-1)) -----
    const f16* h0cur = h0buf + (size_t)p*BATCH*HIDN + (size_t)b0*HIDN;
#pragma unroll
    for (int g=0; g<4; g++)
#pragma unroll
      for (int mt=0; mt<4; mt++)
        acc[g][mt] = splat4(b1v[g]);
    f32x4 fca[4];
#pragma unroll
    for (int mt=0; mt<4; mt++) fca[mt] = splat4(fcbv);

    if (t > 0){
      GEMM(32, [&](int kc){ return kc < 16 ? h0cur + kc*32 : h1rd  + (kc-16)*32; },
               [&](int kc){ return kc < 16 ? Wb1i  + kc*32 : Wb1h + (kc-16)*32; },
           acc, des, fca, 16);
      if (des && ucol < 63){
#pragma unroll
        for (int mt=0; mt<4; mt++)
#pragma unroll
          for (int r=0; r<4; r++){
            int row = wr*64 + mt*16 + quad*4 + r;
            out[((b0+row)*63 + ucol)*100 + (t-1)] = fca[mt][r];
          }
      }
    } else {
      GEMM(16, [&](int kc){ return h0cur + kc*32; },
               [&](int kc){ return Wb1i  + kc*32; },
           acc, false, (f32x4*)nullptr, 0);
    }
#pragma unroll
    for (int mt=0; mt<4; mt++){
#pragma unroll
      for (int r=0; r<4; r++){
        float iv = sigm(acc[0][mt][r]);
        float fv = sigm(acc[1][mt][r]);
        float gv = tanhx(acc[2][mt][r]);
        float ov = sigm(acc[3][mt][r]);
        float cn = fv*c1[mt][r] + iv*gv;
        c1[mt][r] = cn;
        float hn = ov * tanhx(cn);
        int row = wr*64 + mt*16 + quad*4 + r;
        h1wr[(size_t)(b0+row)*HIDN + j*64 + ucol] = (f16)hn;
      }
    }
  }

  // ----- epilogue: y(99) from h1(99) (parity 1), designated block only -----
  barrier(SEQL);
  if (des){
    const f16* h1last = h1buf + (size_t)1*BATCH*HIDN + (size_t)b0*HIDN;
    f32x4 fca[4];
#pragma unroll
    for (int mt=0; mt<4; mt++) fca[mt] = splat4(fcbv);
    for (int kc=0; kc<16; kc++){
      __syncthreads();
      *(u32x4*)&Ach[0][srA*40 + ssg] = *(const u32x4*)(h1last + (size_t)srA*HIDN + kc*32 + ssg);
      __syncthreads();
      half8 af[4];
#pragma unroll
      for (int mt=0; mt<4; mt++)
        af[mt] = *(const half8*)&Ach[0][(wr*64 + mt*16 + lc)*40 + quad*8];
      half8 fb = *(const half8*)(fcWp + (size_t)ucol*HIDN + kc*32 + quad*8);
#pragma unroll
      for (int mt=0; mt<4; mt++)
        fca[mt] = __builtin_amdgcn_mfma_f32_16x16x32_f16(af[mt], fb, fca[mt], 0, 0, 0);
    }
    if (ucol < 63){
#pragma unroll
      for (int mt=0; mt<4; mt++)
#pragma unroll
        for (int r=0; r<4; r++){
          int row = wr*64 + mt*16 + quad*4 + r;
          out[((b0+row)*63 + ucol)*100 + 99] = fca[mt][r];
        }
    }
  }
}

// ---------------------------------------------------------------------------
extern "C" void kernel_launch(void* const* d_in, const int* in_sizes, int n_in,
                              void* d_out, int out_size, void* d_ws, size_t ws_size,
                              hipStream_t stream)
{
  const int*   sl   = (const int*)  d_in[0];
  const int*   el   = (const int*)  d_in[1];
  const float* sc   = (const float*)d_in[2];
  const float* ec   = (const float*)d_in[3];
  const float* emb  = (const float*)d_in[4];
  const float* Wih0 = (const float*)d_in[5];
  const float* Whh0 = (const float*)d_in[6];
  const float* bih0 = (const float*)d_in[7];
  const float* bhh0 = (const float*)d_in[8];
  const float* Wih1 = (const float*)d_in[9];
  const float* Whh1 = (const float*)d_in[10];
  const float* bih1 = (const float*)d_in[11];
  const float* bhh1 = (const float*)d_in[12];
  const float* fcW  = (const float*)d_in[13];
  const float* fcb  = (const float*)d_in[14];

  char* ws = (char*)d_ws;
  float* xcatT = (float*)(ws + OFF_XCAT);
  float* x0pT  = (float*)(ws + OFF_X0PT);
  f16*   Wp0   = (f16*)  (ws + OFF_WP0);
  f16*   Wp1i  = (f16*)  (ws + OFF_WP1I);
  f16*   Wp1h  = (f16*)  (ws + OFF_WP1H);
  f16*   fcWp  = (f16*)  (ws + OFF_FCW);
  float* b1p   = (float*)(ws + OFF_B1P);
  f16*   h0b   = (f16*)  (ws + OFF_H0);
  f16*   h1b   = (f16*)  (ws + OFF_H1);
  unsigned int* flags = (unsigned int*)(ws + OFF_FLAGS);

  hipMemsetAsync(flags, 0, FLAG_BYTES, stream);
  k_xcat<<<dim3(16, 256), 256, 0, stream>>>(sl, el, sc, ec, emb, xcatT);
  k_pack<<<6216, 256, 0, stream>>>(Whh0, Wih1, Whh1, fcW, bih1, bhh1,
                                   Wp0, Wp1i, Wp1h, fcWp, b1p);
  k_x0<<<dim3(128, 16), 256, 0, stream>>>(xcatT, Wih0, bih0, bhh0, x0pT);
  k_lstm<<<256, 512, 0, stream>>>(x0pT, Wp0, Wp1i, Wp1h, fcWp, b1p, fcb,
                                  h0b, h1b, flags, (float*)d_out);
}